// Round 5
// baseline (289.046 us; speedup 1.0000x reference)
//
#include <hip/hip_runtime.h>
#include <hip/hip_bf16.h>

// Fused Conv3d(3->16,k=3,valid) + conv_b + ReLU + maxpool2x2x2
// + spatial mean(fp32) + /2 + bias + channel-sum  ->  out[32] fp32.
//
// R14: amortize per-iteration overhead — 6-slot pair-rotation LDS,
// ONE barrier per 2 dp planes (barriers 15 -> 8).
//  - LDS = 6 pair-slots (slot = d-plane-pair % 6, 130 rows x 64 B = 8320 B
//    each, 49.9 KB total). A slot holds one pair: per (row, hl) 16 B =
//    [even plane: ci0..2+pad][odd plane: ...]. Lane's K-half = slot(dp+hs)
//    -> NO dl-rotation XORs, af table unchanged.
//  - Window t: stage pairs 2t+2,2t+3 -> slots mod 6; BAR; compute dp=2t,
//    dp=2t+1. Next window writes slots {2t+4,2t+5} mod 6, disjoint from
//    this window's read set {2t..2t+2} mod 6 -> no extra barrier; slot
//    rewrite distance = 3 windows (>=1 barrier between read & rewrite).
//  - mixF1 REVERTED (R13 evidence: 3 ds_reads < 24 VALU): 9 plain
//    ds_read_b128 per dp, 18 MFMAs + 18 reads per barrier window (ILP).
//  - Bank shape: write phys = hr ^ ((row>>1)&3) -> <=2-way (free, m136);
//    reads unique & balanced.
// (kept, verified absmax=0): operand-swapped MFMA (M=spatial, N=(ch,dd)),
//  in-register 2x2 pool + DPP dd-pool, stage-2-planes/dp, ci-fast packing,
//  lgkm-only BAR (global loads stay in flight), XCD bijective swizzle.
//  MFMA m32n32k16, D: col=lane&31, row=(reg&3)+8*(reg>>2)+4*(lane>>5).

typedef __attribute__((ext_vector_type(8)))  short  short8;
typedef __attribute__((ext_vector_type(2)))  float  floatx2;
typedef __attribute__((ext_vector_type(4)))  float  floatx4;
typedef __attribute__((ext_vector_type(16))) float  floatx16;

__device__ __forceinline__ short f2bf(float f) {
    unsigned u = __builtin_bit_cast(unsigned, f);
    unsigned r = (u + 0x7FFFu + ((u >> 16) & 1u)) >> 16;
    return (short)r;
}

__device__ __forceinline__ unsigned pkbf2(float a, float b) {
    __hip_bfloat162 h = __float22bfloat162_rn(float2{a, b});  // v_cvt_pk_bf16_f32
    unsigned r;
    __builtin_memcpy(&r, &h, 4);
    return r;
}

template <int CTRL>
__device__ __forceinline__ float dpp_max(float v) {
    int x = __builtin_bit_cast(int, v);
    int y = __builtin_amdgcn_mov_dpp(x, CTRL, 0xF, 0xF, true);
    return fmaxf(v, __builtin_bit_cast(float, y));
}

// LDS-only barrier: drain DS ops, leave global loads in flight (no vmcnt).
#define BAR() asm volatile("s_waitcnt lgkmcnt(0)\n\ts_barrier" ::: "memory")

#define SLOT 8320   // 130 rows x 64 B

// ---- init: wtab[f=kh*3+kw][lane][8] zero-padded B-frags + out = bias sums ----
__global__ void init_kernel(const float* __restrict__ wg,
                            const float* __restrict__ biasg,
                            short* __restrict__ wtab,   // d_ws: 9*64*8 bf16 = 9216 B
                            float* __restrict__ out)    // [32]
{
    const int t = threadIdx.x;               // 0..575
    if (t < 576) {
        const int lane = t & 63, f = t >> 6;
        const int kh = f / 3, kw = f % 3;
        const int m = lane & 31, hs = lane >> 5;
        const int ch = m >> 1, dd = m & 1;   // col = 2*ch + dd
        short8 v;
        #pragma unroll
        for (int j = 0; j < 8; ++j) {
            const int s = hs * 8 + j;        // k-slot: dl_rel = s>>2, ci = s&3
            const int dl = s >> 2, ci = s & 3;
            const int kd = dl - dd;
            v[j] = (ci < 3 && kd >= 0 && kd < 3)
                 ? f2bf(wg[ch * 81 + ci * 27 + kd * 9 + kh * 3 + kw]) : (short)0;
        }
        ((short8*)wtab)[f * 64 + lane] = v;
    }
    if (t < 32) {
        float s = 0.f;
        #pragma unroll
        for (int cc = 0; cc < 16; ++cc) s += biasg[cc];
        out[t] = s;   // conv blocks atomicAdd on top
    }
}

__global__ __launch_bounds__(512, 4) void fused_conv_pool_reduce(
    const float* __restrict__ xg,    // f32 [32][3][32][128][128]
    const short* __restrict__ wtab,  // bf16 frag table in d_ws
    const float* __restrict__ cbg,   // f32 [16]
    float* __restrict__ out)         // f32 [32]
{
    __shared__ __align__(16) short rawT[6 * 130 * 32];  // 49,920 B (6 pair-slots)
    __shared__ float wsums[8];

    // XCD-aware bijective swizzle: 2016 = 8 XCDs x 252 (4 b x 63 hp each).
    const int lin = blockIdx.y * 63 + blockIdx.x;      // 0..2015
    const int nl  = (lin & 7) * 252 + (lin >> 3);
    const int hp  = nl % 63;
    const int b   = nl / 63;

    const int tid = threadIdx.x;  // 0..511
    const int lane = tid & 63;
    const int wv   = tid >> 6;    // wave = 16-wide w tile
    const int hs   = lane >> 5;

    // ---- resident B-frags (36 VGPR), conv-bias, validity masks ----
    short8 af[9];
    #pragma unroll
    for (int f = 0; f < 9; ++f) af[f] = ((const short8*)wtab)[f * 64 + lane];
    const float cbv = cbg[(lane >> 1) & 15];   // ch = (lane&31)>>1
    float maskA[4];
    #pragma unroll
    for (int a = 0; a < 4; ++a) {
        const bool ok = ((lane & 1) == 0) && (wv * 8 + 2 * a + hs <= 62);
        maskA[a] = ok ? 1.0f : 0.0f;
    }

    // ---- zero rows 128/129 of all 6 slots (stage never touches them) ----
    if (tid < 96) {
        const int s = tid >> 4, q = tid & 15;
        *(unsigned long long*)((char*)rawT + s * SLOT + 8192 + q * 8) = 0ULL;
    }

    // ---- stage map: per pair, 2 rows x 8 B per thread ----
    const int w4 = tid & 31, dr2 = (tid >> 5) & 1, rr = (tid >> 6) & 1, hr2 = (tid >> 7) & 3;
    int wad[2];
    #pragma unroll
    for (int j = 0; j < 2; ++j) {
        const int row = 2 * w4 + 64 * rr + j;
        const int phys = hr2 ^ ((row >> 1) & 3);
        wad[j] = row * 64 + phys * 16 + dr2 * 8;
    }

    // ---- read map: row = wv*16 + wi + kw, chunk hl = hh + kh ----
    const int wi = (lane >> 1) & 15, hh = lane & 1;
    int rad[3][3];
    #pragma unroll
    for (int kh = 0; kh < 3; ++kh) {
        #pragma unroll
        for (int kw = 0; kw < 3; ++kw) {
            const int row = wv * 16 + wi + kw;
            const int phys = (hh + kh) ^ ((row >> 1) & 3);
            rad[kh][kw] = row * 64 + phys * 16;
        }
    }

    // ---- prologue: stage pairs 0,1 (planes 0..3) into slots 0,1 ----
    {
        const int w4p = tid & 31, drp = (tid >> 5) & 3, hrp = (tid >> 7) & 3;
        const float* srcP = xg + ((size_t)b * 96 + drp) * 16384 + (2 * hp + hrp) * 128 + 4 * w4p;
        const floatx4 c0 = *(const floatx4*)(srcP);
        const floatx4 c1 = *(const floatx4*)(srcP + 524288);
        const floatx4 c2 = *(const floatx4*)(srcP + 1048576);
        const int slotP = (drp >> 1) * SLOT;
        const int parP  = (drp & 1) * 8;
        #pragma unroll
        for (int i = 0; i < 4; ++i) {
            const int row = 4 * w4p + i;
            const int phys = hrp ^ ((row >> 1) & 3);
            uint2 pk;
            pk.x = pkbf2(c0[i], c1[i]);
            pk.y = pkbf2(c2[i], 0.0f);
            *(uint2*)((char*)rawT + slotP + row * 64 + phys * 16 + parP) = pk;
        }
    }

    // ---- prefetch pairs 2,3 (planes 4..7), float2 per ci ----
    const float* srcE = xg + ((size_t)b * 96 + 4 + dr2) * 16384
                      + (2 * hp + hr2) * 128 + 2 * w4 + 64 * rr;
    const float* srcO = srcE + 32768;   // +2 planes
    floatx2 E0 = *(const floatx2*)(srcE);
    floatx2 E1 = *(const floatx2*)(srcE + 524288);
    floatx2 E2 = *(const floatx2*)(srcE + 1048576);
    floatx2 O0 = *(const floatx2*)(srcO);
    floatx2 O1 = *(const floatx2*)(srcO + 524288);
    floatx2 O2 = *(const floatx2*)(srcO + 1048576);

    float vsum = 0.f;

    auto computeDP = [&](int base) {   // base: per-lane slot base (hs-resolved)
        floatx16 acc = {0.f,0.f,0.f,0.f,0.f,0.f,0.f,0.f,
                        0.f,0.f,0.f,0.f,0.f,0.f,0.f,0.f};
        #pragma unroll
        for (int kh = 0; kh < 3; ++kh) {
            #pragma unroll
            for (int kw = 0; kw < 3; ++kw) {
                const short8 bf = *(const short8*)((char*)rawT + base + rad[kh][kw]);
                acc = __builtin_amdgcn_mfma_f32_32x32x16_bf16(bf, af[kh * 3 + kw], acc, 0, 0, 0);
            }
        }
        // epilogue: acc[4a..4a+3] = one 2x2 h/w window (in-reg max),
        // dd-pool = DPP ^1, then +cb, relu, masked accumulate.
        #pragma unroll
        for (int a = 0; a < 4; ++a) {
            float m01 = fmaxf(acc[4 * a],     acc[4 * a + 1]);
            float m23 = fmaxf(acc[4 * a + 2], acc[4 * a + 3]);
            float m   = fmaxf(m01, m23);
            m = dpp_max<0xB1>(m);                 // pool over dd (lane ^ 1)
            const float v = fmaxf(m + cbv, 0.f);  // +conv_b, relu (post-pool)
            vsum = fmaf(maskA[a], v, vsum);
        }
    };

    // ---- main loop: window t handles dp = 2t, 2t+1 with ONE barrier ----
    int m3 = 0;   // t % 3, maintained incrementally
    for (int t = 0; t < 7; ++t) {
        const int sR0 = m3 * (2 * SLOT);                  // slot (2t)%6
        const int sR1 = sR0 + SLOT;                       // slot (2t+1)%6
        const int sR2 = (m3 == 2) ? 0 : sR0 + 2 * SLOT;   // slot (2t+2)%6
        const int sW3 = (m3 == 2) ? SLOT : sR2 + SLOT;    // slot (2t+3)%6

        // stage pair 2t+2 -> sR2, pair 2t+3 -> sW3
        {
            uint2 p0, p1;
            p0.x = pkbf2(E0[0], E1[0]); p0.y = pkbf2(E2[0], 0.0f);
            p1.x = pkbf2(E0[1], E1[1]); p1.y = pkbf2(E2[1], 0.0f);
            *(uint2*)((char*)rawT + sR2 + wad[0]) = p0;
            *(uint2*)((char*)rawT + sR2 + wad[1]) = p1;
            p0.x = pkbf2(O0[0], O1[0]); p0.y = pkbf2(O2[0], 0.0f);
            p1.x = pkbf2(O0[1], O1[1]); p1.y = pkbf2(O2[1], 0.0f);
            *(uint2*)((char*)rawT + sW3 + wad[0]) = p0;
            *(uint2*)((char*)rawT + sW3 + wad[1]) = p1;
        }
        // prefetch pairs 2t+4, 2t+5 (full window of latency cover)
        if (t < 6) {
            srcE += 65536;  srcO += 65536;   // +4 planes
            E0 = *(const floatx2*)(srcE);
            E1 = *(const floatx2*)(srcE + 524288);
            E2 = *(const floatx2*)(srcE + 1048576);
            O0 = *(const floatx2*)(srcO);
            O1 = *(const floatx2*)(srcO + 524288);
            O2 = *(const floatx2*)(srcO + 1048576);
        }
        BAR();   // LDS-only; next window's writes hit disjoint slots

        computeDP(hs ? sR1 : sR0);   // dp = 2t   (pairs 2t, 2t+1)
        computeDP(hs ? sR2 : sR1);   // dp = 2t+1 (pairs 2t+1, 2t+2)

        m3 = (m3 == 2) ? 0 : m3 + 1;
    }
    // tail dp = 14 (pairs 14,15 in slots 2,3; staged before t=6's BAR)
    computeDP(hs ? 3 * SLOT : 2 * SLOT);

    // mask already zeroes invalid lanes/groups: plain full-wave sum
    float s = vsum;
    #pragma unroll
    for (int off = 1; off < 64; off <<= 1) s += __shfl_xor(s, off, 64);

    if (lane == 0) wsums[wv] = s;
    __syncthreads();
    if (tid == 0) {
        float bs = 0.f;
        #pragma unroll
        for (int i = 0; i < 8; ++i) bs += wsums[i];
        atomicAdd(&out[b], bs * (1.0f / 119070.0f));   // /(15*63*63)/2
    }
}

extern "C" void kernel_launch(void* const* d_in, const int* in_sizes, int n_in,
                              void* d_out, int out_size, void* d_ws, size_t ws_size,
                              hipStream_t stream) {
    const float* x      = (const float*)d_in[0];
    const float* conv_w = (const float*)d_in[1];
    const float* conv_b = (const float*)d_in[2];
    const float* bias   = (const float*)d_in[3];
    float* out = (float*)d_out;
    short* wtab = (short*)d_ws;   // 9216 B

    init_kernel<<<1, 576, 0, stream>>>(conv_w, bias, wtab, out);
    dim3 grid(63, 32);  // (hp, b) pre-swizzle
    fused_conv_pool_reduce<<<grid, 512, 0, stream>>>(x, wtab, conv_b, out);
}